// Round 1
// baseline (281.412 us; speedup 1.0000x reference)
//
#include <hip/hip_runtime.h>
#include <hip/hip_bf16.h>

// B=4, S=2048, D=1024.  M = B*S = 8192.
// Workspace layout (bytes), total 117,440,512 (112 MB):
//   [0,         67108864)  : scores fp32 (4*2048*2048)      -- written by qk_gemm
//     overlay (dead before qk_gemm runs):
//     [0,         16777216) : Xb  bf16 (8192*1024)
//     [16777216,  23068672) : Wt  bf16 (3072*1024)
//     [23068672,  39845888) : V   bf16 (8192*1024)
//   [67108864,  100663296) : P bf16 (4*2048*2048)           -- written by softmax
//     overlay (dead before softmax runs):
//     [67108864,  83886080) : Q bf16 (8192*1024)
//     [83886080, 100663296) : K bf16 (8192*1024)
//   [100663296, 117440512) : Vt bf16 (4*1024*2048)

typedef __attribute__((ext_vector_type(8))) short short8;
typedef __attribute__((ext_vector_type(4))) short s16x4;
typedef __attribute__((ext_vector_type(4))) float f32x4;

__device__ __forceinline__ short f2bf(float f) {
  __hip_bfloat16 h = __float2bfloat16(f);
  return *reinterpret_cast<short*>(&h);
}

__device__ __forceinline__ void gll16(const void* g, void* l) {
  __builtin_amdgcn_global_load_lds((const __attribute__((address_space(1))) void*)g,
                                   (__attribute__((address_space(3))) void*)l,
                                   16, 0, 0);
}

// ---------------------------------------------------------------------------
// Shared 128x128-tile GEMM core: C = A[M][K] * Bt[N][K]^T  (bf16, fp32 acc)
// 256 threads = 4 waves in 2x2 arrangement; each wave owns 4x4 16x16 tiles.
// BK=32. LDS tiles staged with global_load_lds width=16 (lane-contiguous).
// ---------------------------------------------------------------------------
__device__ __forceinline__ void gemm_core(const short* __restrict__ A,
                                          const short* __restrict__ Bt,
                                          int lda, int ldb,
                                          int row0, int col0, int kIters,
                                          f32x4 acc[4][4],
                                          short* lA, short* lB) {
  const int tid  = threadIdx.x;
  const int wave = tid >> 6;
  const int lane = tid & 63;
  const int quad = lane >> 4;
  const int l16  = lane & 15;

  const f32x4 zero = {0.f, 0.f, 0.f, 0.f};
#pragma unroll
  for (int i = 0; i < 4; ++i)
#pragma unroll
    for (int j = 0; j < 4; ++j) acc[i][j] = zero;

  // staging: chunk c (0..511) = 16B: row = c>>2, koff = (c&3)*8.
  // thread t handles chunks t and t+256; LDS dest = chunk*16B (lane-contiguous)
  const int lrow = tid >> 2;
  const int lcol = (tid & 3) * 8;
  const short* A1 = A + (size_t)(row0 + lrow) * lda + lcol;
  const short* A2 = A + (size_t)(row0 + lrow + 64) * lda + lcol;
  const short* B1 = Bt + (size_t)(col0 + lrow) * ldb + lcol;
  const short* B2 = Bt + (size_t)(col0 + lrow + 64) * ldb + lcol;

  short* lA1 = lA + wave * 512;          // wave-uniform LDS bases
  short* lA2 = lA + 2048 + wave * 512;
  short* lB1 = lB + wave * 512;
  short* lB2 = lB + 2048 + wave * 512;

  // fragment read bases: A[m=l16][k=quad*8..], Bt[n=l16][k=quad*8..]
  const short* aBase = lA + ((wave >> 1) * 64 + l16) * 32 + quad * 8;
  const short* bBase = lB + ((wave & 1) * 64 + l16) * 32 + quad * 8;

  for (int it = 0; it < kIters; ++it) {
    const int k0 = it * 32;
    gll16(A1 + k0, lA1);
    gll16(A2 + k0, lA2);
    gll16(B1 + k0, lB1);
    gll16(B2 + k0, lB2);
    __syncthreads();   // drains vmcnt before barrier

    short8 af[4], bfr[4];
#pragma unroll
    for (int i = 0; i < 4; ++i) af[i] = *(const short8*)(aBase + i * 16 * 32);
#pragma unroll
    for (int j = 0; j < 4; ++j) bfr[j] = *(const short8*)(bBase + j * 16 * 32);
#pragma unroll
    for (int i = 0; i < 4; ++i)
#pragma unroll
      for (int j = 0; j < 4; ++j)
        acc[i][j] = __builtin_amdgcn_mfma_f32_16x16x32_bf16(af[i], bfr[j], acc[i][j], 0, 0, 0);
    __syncthreads();
  }
}

// C/D layout: row = quad*4 + reg, col = l16  (verified m89)
#define EPILOGUE_VARS                         \
  const int lane = threadIdx.x & 63;          \
  const int wave = threadIdx.x >> 6;          \
  const int quad = lane >> 4;                 \
  const int l16  = lane & 15;                 \
  const int rb   = (wave >> 1) * 64;          \
  const int cb   = (wave & 1) * 64;

// ---------------------------------------------------------------------------
__global__ __launch_bounds__(256) void cast_x_kernel(const float* __restrict__ X,
                                                     short* __restrict__ Xb) {
  const int i = (blockIdx.x * 256 + threadIdx.x) * 4;
  const f32x4 v = *(const f32x4*)(X + i);
  s16x4 o;
  o.x = f2bf(v.x); o.y = f2bf(v.y); o.z = f2bf(v.z); o.w = f2bf(v.w);
  *(s16x4*)(Xb + i) = o;
}

// W[1024][3072] fp32 -> Wt[3072][1024] bf16, tiled 32x32 transpose
__global__ __launch_bounds__(256) void transpose_w_kernel(const float* __restrict__ W,
                                                          short* __restrict__ Wt) {
  __shared__ float tile[32][33];
  const int ni = blockIdx.x % 96;
  const int ki = blockIdx.x / 96;
  const int tx = threadIdx.x & 31;
  const int ty = threadIdx.x >> 5;  // 0..7
#pragma unroll
  for (int rr = 0; rr < 4; ++rr) {
    const int k = ki * 32 + ty + rr * 8;
    const int n = ni * 32 + tx;
    tile[ty + rr * 8][tx] = W[(size_t)k * 3072 + n];
  }
  __syncthreads();
#pragma unroll
  for (int rr = 0; rr < 4; ++rr) {
    const int n = ni * 32 + ty + rr * 8;
    const int k = ki * 32 + tx;
    Wt[(size_t)n * 1024 + k] = f2bf(tile[tx][ty + rr * 8]);
  }
}

// V[b][2048][1024] -> Vt[b][1024][2048] (bf16), 32x32 tiles, 2048 blocks/batch
__global__ __launch_bounds__(256) void transpose_v_kernel(const short* __restrict__ V,
                                                          short* __restrict__ Vt) {
  __shared__ short tile[32][33];
  const int b  = blockIdx.x >> 11;
  const int r  = blockIdx.x & 2047;
  const int si = r >> 5;   // 0..63
  const int di = r & 31;   // 0..31
  const short* Vb  = V + (size_t)b * 2048 * 1024;
  short*       Vtb = Vt + (size_t)b * 1024 * 2048;
  const int tx = threadIdx.x & 31;
  const int ty = threadIdx.x >> 5;
#pragma unroll
  for (int rr = 0; rr < 4; ++rr) {
    const int s = si * 32 + ty + rr * 8;
    const int d = di * 32 + tx;
    tile[ty + rr * 8][tx] = Vb[(size_t)s * 1024 + d];
  }
  __syncthreads();
#pragma unroll
  for (int rr = 0; rr < 4; ++rr) {
    const int d = di * 32 + ty + rr * 8;
    const int s = si * 32 + tx;
    Vtb[(size_t)d * 2048 + s] = tile[tx][ty + rr * 8];
  }
}

// QKV: [8192x1024] x Wt[3072x1024]^T -> Q,K,V bf16 (column split)
__global__ __launch_bounds__(256) void qkv_gemm_kernel(const short* __restrict__ Xb,
                                                       const short* __restrict__ Wt,
                                                       short* __restrict__ Q,
                                                       short* __restrict__ K,
                                                       short* __restrict__ V) {
  __shared__ short lA[4096], lB[4096];
  const int br = blockIdx.x / 24;   // 64 row tiles
  const int bc = blockIdx.x % 24;   // 24 col tiles
  f32x4 acc[4][4];
  gemm_core(Xb, Wt, 1024, 1024, br * 128, bc * 128, 32, acc, lA, lB);

  EPILOGUE_VARS
  const int rbase = br * 128 + rb;
  const int cbase = bc * 128 + cb;
#pragma unroll
  for (int i = 0; i < 4; ++i)
#pragma unroll
    for (int j = 0; j < 4; ++j) {
      const int col = cbase + j * 16 + l16;
      short* dst;
      int n;
      if (col < 1024)      { dst = Q; n = col; }
      else if (col < 2048) { dst = K; n = col - 1024; }
      else                 { dst = V; n = col - 2048; }
#pragma unroll
      for (int r = 0; r < 4; ++r) {
        const int row = rbase + i * 16 + quad * 4 + r;
        dst[(size_t)row * 1024 + n] = f2bf(acc[i][j][r]);
      }
    }
}

// scores = Q*K^T * (1/32), lower-triangle 128x128 tiles only. 544 blocks.
__global__ __launch_bounds__(256) void qk_gemm_kernel(const short* __restrict__ Q,
                                                      const short* __restrict__ K,
                                                      float* __restrict__ Sc) {
  const int b  = blockIdx.x / 136;
  const int tt = blockIdx.x % 136;
  int qi = 0;
  while ((qi + 1) * (qi + 2) / 2 <= tt) qi++;
  const int ki = tt - qi * (qi + 1) / 2;

  __shared__ short lA[4096], lB[4096];
  f32x4 acc[4][4];
  const short* Qb = Q + (size_t)b * 2048 * 1024;
  const short* Kb = K + (size_t)b * 2048 * 1024;
  gemm_core(Qb, Kb, 1024, 1024, qi * 128, ki * 128, 32, acc, lA, lB);

  EPILOGUE_VARS
  float* Sb = Sc + (size_t)b * 2048 * 2048;
  const int rbase = qi * 128 + rb;
  const int cbase = ki * 128 + cb;
#pragma unroll
  for (int i = 0; i < 4; ++i)
#pragma unroll
    for (int j = 0; j < 4; ++j) {
      const int col = cbase + j * 16 + l16;
#pragma unroll
      for (int r = 0; r < 4; ++r) {
        const int row = rbase + i * 16 + quad * 4 + r;
        Sb[(size_t)row * 2048 + col] = acc[i][j][r] * 0.03125f;
      }
    }
}

// row softmax with causal mask (reads only k<=q); writes P bf16, zero-padded
// up to the 128-tile boundary so pv_gemm can read whole tiles.
__global__ __launch_bounds__(256) void softmax_kernel(const float* __restrict__ Sc,
                                                      short* __restrict__ P) {
  const int q = blockIdx.x & 2047;
  const int b = blockIdx.x >> 11;
  const float* srow = Sc + ((size_t)(b * 2048 + q)) * 2048;
  short*       prow = P + ((size_t)(b * 2048 + q)) * 2048;
  const int n   = q + 1;
  const int tid = threadIdx.x;

  float v[8];
  float m = -3.0e38f;
#pragma unroll
  for (int c = 0; c < 8; ++c) {
    const int k = tid + c * 256;
    v[c] = (k < n) ? srow[k] : -3.0e38f;
    m = fmaxf(m, v[c]);
  }
#pragma unroll
  for (int off = 32; off > 0; off >>= 1) m = fmaxf(m, __shfl_xor(m, off));
  __shared__ float redm[4];
  if ((tid & 63) == 0) redm[tid >> 6] = m;
  __syncthreads();
  m = fmaxf(fmaxf(redm[0], redm[1]), fmaxf(redm[2], redm[3]));

  float e[8];
  float s = 0.f;
#pragma unroll
  for (int c = 0; c < 8; ++c) {
    const int k = tid + c * 256;
    e[c] = (k < n) ? __expf(v[c] - m) : 0.f;
    s += e[c];
  }
#pragma unroll
  for (int off = 32; off > 0; off >>= 1) s += __shfl_xor(s, off);
  __shared__ float reds[4];
  if ((tid & 63) == 0) reds[tid >> 6] = s;
  __syncthreads();
  s = reds[0] + reds[1] + reds[2] + reds[3];
  const float inv = 1.f / s;

  const int kend = ((q >> 7) + 1) << 7;
#pragma unroll
  for (int c = 0; c < 8; ++c) {
    const int k = tid + c * 256;
    if (k < kend) prow[k] = (k < n) ? f2bf(e[c] * inv) : (short)0;
  }
}

// out = P * V   (A = P[2048x2048] bf16, Bt = Vt[1024x2048] bf16)
// per-q-tile k-limit (causal). Heavy tiles (large qi) scheduled first.
__global__ __launch_bounds__(256) void pv_gemm_kernel(const short* __restrict__ P,
                                                      const short* __restrict__ Vt,
                                                      float* __restrict__ out) {
  const int b  = blockIdx.x >> 7;         // 128 tiles per batch
  const int r  = blockIdx.x & 127;
  const int qi = 15 - (r >> 3);           // descending work order
  const int dj = r & 7;

  __shared__ short lA[4096], lB[4096];
  f32x4 acc[4][4];
  const short* Pb  = P + (size_t)b * 2048 * 2048;
  const short* Vtb = Vt + (size_t)b * 1024 * 2048;
  gemm_core(Pb, Vtb, 2048, 2048, qi * 128, dj * 128, (qi + 1) * 4, acc, lA, lB);

  EPILOGUE_VARS
  float* ob = out + (size_t)b * 2048 * 1024;
  const int rbase = qi * 128 + rb;
  const int cbase = dj * 128 + cb;
#pragma unroll
  for (int i = 0; i < 4; ++i)
#pragma unroll
    for (int j = 0; j < 4; ++j) {
      const int col = cbase + j * 16 + l16;
#pragma unroll
      for (int r2 = 0; r2 < 4; ++r2) {
        const int row = rbase + i * 16 + quad * 4 + r2;
        ob[(size_t)row * 1024 + col] = acc[i][j][r2];
      }
    }
}

// ---------------------------------------------------------------------------
extern "C" void kernel_launch(void* const* d_in, const int* in_sizes, int n_in,
                              void* d_out, int out_size, void* d_ws, size_t ws_size,
                              hipStream_t stream) {
  const float* X = (const float*)d_in[0];
  const float* W = (const float*)d_in[1];
  float* out = (float*)d_out;
  char* w = (char*)d_ws;

  short* Xb = (short*)(w + 0);
  short* Wt = (short*)(w + 16777216);
  short* V  = (short*)(w + 23068672);
  float* Sc = (float*)(w + 0);
  short* Q  = (short*)(w + 67108864);
  short* K  = (short*)(w + 83886080);
  short* P  = (short*)(w + 67108864);   // overlays Q,K (dead by then)
  short* Vt = (short*)(w + 100663296);

  hipLaunchKernelGGL(cast_x_kernel,      dim3(8192), dim3(256), 0, stream, X, Xb);
  hipLaunchKernelGGL(transpose_w_kernel, dim3(3072), dim3(256), 0, stream, W, Wt);
  hipLaunchKernelGGL(qkv_gemm_kernel,    dim3(1536), dim3(256), 0, stream, Xb, Wt, Q, K, V);
  hipLaunchKernelGGL(transpose_v_kernel, dim3(8192), dim3(256), 0, stream, V, Vt);
  hipLaunchKernelGGL(qk_gemm_kernel,     dim3(544),  dim3(256), 0, stream, Q, K, Sc);
  hipLaunchKernelGGL(softmax_kernel,     dim3(8192), dim3(256), 0, stream, Sc, P);
  hipLaunchKernelGGL(pv_gemm_kernel,     dim3(512),  dim3(256), 0, stream, P, Vt, out);
}

// Round 2
// 280.320 us; speedup vs baseline: 1.0039x; 1.0039x over previous
//
#include <hip/hip_runtime.h>
#include <hip/hip_bf16.h>

// B=4, S=2048, D=1024.  M = B*S = 8192.
// Workspace layout (bytes), total 117,440,512 (112 MB):
//   [0,         67108864)  : scores fp32 (4*2048*2048)      -- written by qk_gemm
//     overlay (dead before qk_gemm runs):
//     [0,         16777216) : Xb  bf16 (8192*1024)
//     [16777216,  23068672) : Wt  bf16 (3072*1024)
//     [23068672,  39845888) : V   bf16 (8192*1024)
//   [67108864,  100663296) : P bf16 (4*2048*2048)           -- written by softmax
//     overlay (dead before softmax runs):
//     [67108864,  83886080) : Q bf16 (8192*1024)
//     [83886080, 100663296) : K bf16 (8192*1024)
//   [100663296, 117440512) : Vt bf16 (4*1024*2048)

typedef __attribute__((ext_vector_type(8))) short short8;
typedef __attribute__((ext_vector_type(4))) short s16x4;
typedef __attribute__((ext_vector_type(4))) float f32x4;

__device__ __forceinline__ short f2bf(float f) {
  __hip_bfloat16 h = __float2bfloat16(f);
  return *reinterpret_cast<short*>(&h);
}

__device__ __forceinline__ void gll16(const void* g, void* l) {
  __builtin_amdgcn_global_load_lds((const __attribute__((address_space(1))) void*)g,
                                   (__attribute__((address_space(3))) void*)l,
                                   16, 0, 0);
}

// ---------------------------------------------------------------------------
// Shared 128x128-tile GEMM core: C = A[M][K] * Bt[N][K]^T  (bf16, fp32 acc)
// 256 threads = 4 waves in 2x2 arrangement; each wave owns 4x4 16x16 tiles.
// BK=32. LDS tiles staged with global_load_lds width=16 (lane-contiguous).
//
// Bank-conflict swizzle: LDS tile row r stores its four 16B k-groups
// permuted by XOR with ((r>>1)&3).  global_load_lds forces LDS dest =
// base + lane*16B, so the permutation is applied on the GLOBAL source
// address at staging time, and undone at fragment-read time via
// gl = quad ^ ((l16>>1)&3).  This turns the 8-way ds_read_b128 bank
// conflict (16*l16 mod 32 -> {0,16}) into a free 2-way (m136).
// ---------------------------------------------------------------------------
__device__ __forceinline__ void gemm_core(const short* __restrict__ A,
                                          const short* __restrict__ Bt,
                                          int lda, int ldb,
                                          int row0, int col0, int kIters,
                                          f32x4 acc[4][4],
                                          short* lA, short* lB) {
  const int tid  = threadIdx.x;
  const int wave = tid >> 6;
  const int lane = tid & 63;
  const int quad = lane >> 4;
  const int l16  = lane & 15;

  const f32x4 zero = {0.f, 0.f, 0.f, 0.f};
#pragma unroll
  for (int i = 0; i < 4; ++i)
#pragma unroll
    for (int j = 0; j < 4; ++j) acc[i][j] = zero;

  // staging: thread t owns LDS chunks t and t+256 (16B each).
  // LDS chunk = (row, slot);  global k-group fetched = slot ^ swz(row).
  // ((row+64)>>1)&3 == (row>>1)&3, so one swz serves both tile halves.
  const int lrow = tid >> 2;
  const int swz  = (lrow >> 1) & 3;
  const int lcol = ((tid & 3) ^ swz) * 8;
  const short* A1 = A + (size_t)(row0 + lrow) * lda + lcol;
  const short* A2 = A + (size_t)(row0 + lrow + 64) * lda + lcol;
  const short* B1 = Bt + (size_t)(col0 + lrow) * ldb + lcol;
  const short* B2 = Bt + (size_t)(col0 + lrow + 64) * ldb + lcol;

  short* lA1 = lA + wave * 512;          // wave-uniform LDS bases
  short* lA2 = lA + 2048 + wave * 512;
  short* lB1 = lB + wave * 512;
  short* lB2 = lB + 2048 + wave * 512;

  // fragment read bases: A[m][k-group quad], un-swizzled.
  // ((i*16+l16)>>1)&3 == (l16>>1)&3, so the base is i-independent.
  const int rswz = (l16 >> 1) & 3;
  const short* aBase = lA + ((wave >> 1) * 64 + l16) * 32 + (quad ^ rswz) * 8;
  const short* bBase = lB + ((wave & 1) * 64 + l16) * 32 + (quad ^ rswz) * 8;

  for (int it = 0; it < kIters; ++it) {
    const int k0 = it * 32;
    gll16(A1 + k0, lA1);
    gll16(A2 + k0, lA2);
    gll16(B1 + k0, lB1);
    gll16(B2 + k0, lB2);
    __syncthreads();   // drains vmcnt before barrier

    short8 af[4], bfr[4];
#pragma unroll
    for (int i = 0; i < 4; ++i) af[i] = *(const short8*)(aBase + i * 16 * 32);
#pragma unroll
    for (int j = 0; j < 4; ++j) bfr[j] = *(const short8*)(bBase + j * 16 * 32);
#pragma unroll
    for (int i = 0; i < 4; ++i)
#pragma unroll
      for (int j = 0; j < 4; ++j)
        acc[i][j] = __builtin_amdgcn_mfma_f32_16x16x32_bf16(af[i], bfr[j], acc[i][j], 0, 0, 0);
    __syncthreads();
  }
}

// C/D layout: row = quad*4 + reg, col = l16  (verified m89)
#define EPILOGUE_VARS                         \
  const int lane = threadIdx.x & 63;          \
  const int wave = threadIdx.x >> 6;          \
  const int quad = lane >> 4;                 \
  const int l16  = lane & 15;                 \
  const int rb   = (wave >> 1) * 64;          \
  const int cb   = (wave & 1) * 64;

// ---------------------------------------------------------------------------
__global__ __launch_bounds__(256) void cast_x_kernel(const float* __restrict__ X,
                                                     short* __restrict__ Xb) {
  const int i = (blockIdx.x * 256 + threadIdx.x) * 4;
  const f32x4 v = *(const f32x4*)(X + i);
  s16x4 o;
  o.x = f2bf(v.x); o.y = f2bf(v.y); o.z = f2bf(v.z); o.w = f2bf(v.w);
  *(s16x4*)(Xb + i) = o;
}

// W[1024][3072] fp32 -> Wt[3072][1024] bf16, tiled 32x32 transpose
__global__ __launch_bounds__(256) void transpose_w_kernel(const float* __restrict__ W,
                                                          short* __restrict__ Wt) {
  __shared__ float tile[32][33];
  const int ni = blockIdx.x % 96;
  const int ki = blockIdx.x / 96;
  const int tx = threadIdx.x & 31;
  const int ty = threadIdx.x >> 5;  // 0..7
#pragma unroll
  for (int rr = 0; rr < 4; ++rr) {
    const int k = ki * 32 + ty + rr * 8;
    const int n = ni * 32 + tx;
    tile[ty + rr * 8][tx] = W[(size_t)k * 3072 + n];
  }
  __syncthreads();
#pragma unroll
  for (int rr = 0; rr < 4; ++rr) {
    const int n = ni * 32 + ty + rr * 8;
    const int k = ki * 32 + tx;
    Wt[(size_t)n * 1024 + k] = f2bf(tile[tx][ty + rr * 8]);
  }
}

// V[b][2048][1024] -> Vt[b][1024][2048] (bf16), 32x32 tiles, 2048 blocks/batch
__global__ __launch_bounds__(256) void transpose_v_kernel(const short* __restrict__ V,
                                                          short* __restrict__ Vt) {
  __shared__ short tile[32][33];
  const int b  = blockIdx.x >> 11;
  const int r  = blockIdx.x & 2047;
  const int si = r >> 5;   // 0..63
  const int di = r & 31;   // 0..31
  const short* Vb  = V + (size_t)b * 2048 * 1024;
  short*       Vtb = Vt + (size_t)b * 1024 * 2048;
  const int tx = threadIdx.x & 31;
  const int ty = threadIdx.x >> 5;
#pragma unroll
  for (int rr = 0; rr < 4; ++rr) {
    const int s = si * 32 + ty + rr * 8;
    const int d = di * 32 + tx;
    tile[ty + rr * 8][tx] = Vb[(size_t)s * 1024 + d];
  }
  __syncthreads();
#pragma unroll
  for (int rr = 0; rr < 4; ++rr) {
    const int d = di * 32 + ty + rr * 8;
    const int s = si * 32 + tx;
    Vtb[(size_t)d * 2048 + s] = tile[tx][ty + rr * 8];
  }
}

// QKV: [8192x1024] x Wt[3072x1024]^T -> Q,K,V bf16 (column split)
__global__ __launch_bounds__(256) void qkv_gemm_kernel(const short* __restrict__ Xb,
                                                       const short* __restrict__ Wt,
                                                       short* __restrict__ Q,
                                                       short* __restrict__ K,
                                                       short* __restrict__ V) {
  __shared__ short lA[4096], lB[4096];
  const int br = blockIdx.x / 24;   // 64 row tiles
  const int bc = blockIdx.x % 24;   // 24 col tiles
  f32x4 acc[4][4];
  gemm_core(Xb, Wt, 1024, 1024, br * 128, bc * 128, 32, acc, lA, lB);

  EPILOGUE_VARS
  const int rbase = br * 128 + rb;
  const int cbase = bc * 128 + cb;
#pragma unroll
  for (int i = 0; i < 4; ++i)
#pragma unroll
    for (int j = 0; j < 4; ++j) {
      const int col = cbase + j * 16 + l16;
      short* dst;
      int n;
      if (col < 1024)      { dst = Q; n = col; }
      else if (col < 2048) { dst = K; n = col - 1024; }
      else                 { dst = V; n = col - 2048; }
#pragma unroll
      for (int r = 0; r < 4; ++r) {
        const int row = rbase + i * 16 + quad * 4 + r;
        dst[(size_t)row * 1024 + n] = f2bf(acc[i][j][r]);
      }
    }
}

// scores = Q*K^T * (1/32), lower-triangle 128x128 tiles only. 544 blocks.
__global__ __launch_bounds__(256) void qk_gemm_kernel(const short* __restrict__ Q,
                                                      const short* __restrict__ K,
                                                      float* __restrict__ Sc) {
  const int b  = blockIdx.x / 136;
  const int tt = blockIdx.x % 136;
  int qi = 0;
  while ((qi + 1) * (qi + 2) / 2 <= tt) qi++;
  const int ki = tt - qi * (qi + 1) / 2;

  __shared__ short lA[4096], lB[4096];
  f32x4 acc[4][4];
  const short* Qb = Q + (size_t)b * 2048 * 1024;
  const short* Kb = K + (size_t)b * 2048 * 1024;
  gemm_core(Qb, Kb, 1024, 1024, qi * 128, ki * 128, 32, acc, lA, lB);

  EPILOGUE_VARS
  float* Sb = Sc + (size_t)b * 2048 * 2048;
  const int rbase = qi * 128 + rb;
  const int cbase = ki * 128 + cb;
#pragma unroll
  for (int i = 0; i < 4; ++i)
#pragma unroll
    for (int j = 0; j < 4; ++j) {
      const int col = cbase + j * 16 + l16;
#pragma unroll
      for (int r = 0; r < 4; ++r) {
        const int row = rbase + i * 16 + quad * 4 + r;
        Sb[(size_t)row * 2048 + col] = acc[i][j][r] * 0.03125f;
      }
    }
}

// row softmax with causal mask (reads only k<=q); writes P bf16, zero-padded
// up to the 128-tile boundary so pv_gemm can read whole tiles.
__global__ __launch_bounds__(256) void softmax_kernel(const float* __restrict__ Sc,
                                                      short* __restrict__ P) {
  const int q = blockIdx.x & 2047;
  const int b = blockIdx.x >> 11;
  const float* srow = Sc + ((size_t)(b * 2048 + q)) * 2048;
  short*       prow = P + ((size_t)(b * 2048 + q)) * 2048;
  const int n   = q + 1;
  const int tid = threadIdx.x;

  float v[8];
  float m = -3.0e38f;
#pragma unroll
  for (int c = 0; c < 8; ++c) {
    const int k = tid + c * 256;
    v[c] = (k < n) ? srow[k] : -3.0e38f;
    m = fmaxf(m, v[c]);
  }
#pragma unroll
  for (int off = 32; off > 0; off >>= 1) m = fmaxf(m, __shfl_xor(m, off));
  __shared__ float redm[4];
  if ((tid & 63) == 0) redm[tid >> 6] = m;
  __syncthreads();
  m = fmaxf(fmaxf(redm[0], redm[1]), fmaxf(redm[2], redm[3]));

  float e[8];
  float s = 0.f;
#pragma unroll
  for (int c = 0; c < 8; ++c) {
    const int k = tid + c * 256;
    e[c] = (k < n) ? __expf(v[c] - m) : 0.f;
    s += e[c];
  }
#pragma unroll
  for (int off = 32; off > 0; off >>= 1) s += __shfl_xor(s, off);
  __shared__ float reds[4];
  if ((tid & 63) == 0) reds[tid >> 6] = s;
  __syncthreads();
  s = reds[0] + reds[1] + reds[2] + reds[3];
  const float inv = 1.f / s;

  const int kend = ((q >> 7) + 1) << 7;
#pragma unroll
  for (int c = 0; c < 8; ++c) {
    const int k = tid + c * 256;
    if (k < kend) prow[k] = (k < n) ? f2bf(e[c] * inv) : (short)0;
  }
}

// out = P * V   (A = P[2048x2048] bf16, Bt = Vt[1024x2048] bf16)
// per-q-tile k-limit (causal). Heavy tiles (large qi) scheduled first.
__global__ __launch_bounds__(256) void pv_gemm_kernel(const short* __restrict__ P,
                                                      const short* __restrict__ Vt,
                                                      float* __restrict__ out) {
  const int b  = blockIdx.x >> 7;         // 128 tiles per batch
  const int r  = blockIdx.x & 127;
  const int qi = 15 - (r >> 3);           // descending work order
  const int dj = r & 7;

  __shared__ short lA[4096], lB[4096];
  f32x4 acc[4][4];
  const short* Pb  = P + (size_t)b * 2048 * 2048;
  const short* Vtb = Vt + (size_t)b * 1024 * 2048;
  gemm_core(Pb, Vtb, 2048, 2048, qi * 128, dj * 128, (qi + 1) * 4, acc, lA, lB);

  EPILOGUE_VARS
  float* ob = out + (size_t)b * 2048 * 1024;
  const int rbase = qi * 128 + rb;
  const int cbase = dj * 128 + cb;
#pragma unroll
  for (int i = 0; i < 4; ++i)
#pragma unroll
    for (int j = 0; j < 4; ++j) {
      const int col = cbase + j * 16 + l16;
#pragma unroll
      for (int r2 = 0; r2 < 4; ++r2) {
        const int row = rbase + i * 16 + quad * 4 + r2;
        ob[(size_t)row * 1024 + col] = acc[i][j][r2];
      }
    }
}

// ---------------------------------------------------------------------------
extern "C" void kernel_launch(void* const* d_in, const int* in_sizes, int n_in,
                              void* d_out, int out_size, void* d_ws, size_t ws_size,
                              hipStream_t stream) {
  const float* X = (const float*)d_in[0];
  const float* W = (const float*)d_in[1];
  float* out = (float*)d_out;
  char* w = (char*)d_ws;

  short* Xb = (short*)(w + 0);
  short* Wt = (short*)(w + 16777216);
  short* V  = (short*)(w + 23068672);
  float* Sc = (float*)(w + 0);
  short* Q  = (short*)(w + 67108864);
  short* K  = (short*)(w + 83886080);
  short* P  = (short*)(w + 67108864);   // overlays Q,K (dead by then)
  short* Vt = (short*)(w + 100663296);

  hipLaunchKernelGGL(cast_x_kernel,      dim3(8192), dim3(256), 0, stream, X, Xb);
  hipLaunchKernelGGL(transpose_w_kernel, dim3(3072), dim3(256), 0, stream, W, Wt);
  hipLaunchKernelGGL(qkv_gemm_kernel,    dim3(1536), dim3(256), 0, stream, Xb, Wt, Q, K, V);
  hipLaunchKernelGGL(transpose_v_kernel, dim3(8192), dim3(256), 0, stream, V, Vt);
  hipLaunchKernelGGL(qk_gemm_kernel,     dim3(544),  dim3(256), 0, stream, Q, K, Sc);
  hipLaunchKernelGGL(softmax_kernel,     dim3(8192), dim3(256), 0, stream, Sc, P);
  hipLaunchKernelGGL(pv_gemm_kernel,     dim3(512),  dim3(256), 0, stream, P, Vt, out);
}

// Round 3
// 261.476 us; speedup vs baseline: 1.0762x; 1.0721x over previous
//
#include <hip/hip_runtime.h>
#include <hip/hip_bf16.h>

// B=4, S=2048, D=1024.  M = B*S = 8192.
// Workspace layout (bytes), total 112 MB:
//   [0,         33554432)  : E bf16 (4*2048*2048) = exp(scores) -- written by qk
//     overlay (dead before qk runs):
//     [0,         16777216) : Xb  bf16 (8192*1024)
//     [16777216,  23068672) : Wt  bf16 (3072*1024)
//   [33554432,  50331648)  : V   bf16 (8192*1024)
//   [50331648,  50364416)  : rowsum fp32 (8192)  (zeroed by setup kernel)
//   [67108864,  83886080)  : Q bf16 (8192*1024)
//   [83886080, 100663296)  : K bf16 (8192*1024)
//   [100663296,117440512)  : Vt bf16 (4*1024*2048)
//
// Pipeline (4 launches):
//   setup   : cast X->bf16, transpose W -> Wt bf16, zero rowsum
//   qkv     : [8192x1024] x Wt^T -> Q,K,V
//   qk+tv   : lower-tri tiles E=exp(QK^T/32) + row-partial sums (atomicAdd);
//             co-scheduled extra blocks transpose V -> Vt (fills idle CUs)
//   pv      : out = (E x V) / rowsum   (per-q-tile causal k-limit)

typedef __attribute__((ext_vector_type(8))) short short8;
typedef __attribute__((ext_vector_type(4))) short s16x4;
typedef __attribute__((ext_vector_type(4))) float f32x4;

__device__ __forceinline__ short f2bf(float f) {
  __hip_bfloat16 h = __float2bfloat16(f);
  return *reinterpret_cast<short*>(&h);
}

__device__ __forceinline__ void gll16(const void* g, void* l) {
  __builtin_amdgcn_global_load_lds((const __attribute__((address_space(1))) void*)g,
                                   (__attribute__((address_space(3))) void*)l,
                                   16, 0, 0);
}

// ---------------------------------------------------------------------------
// Shared 128x128-tile GEMM core: C = A[M][K] * Bt[N][K]^T  (bf16, fp32 acc)
// 256 threads = 4 waves in 2x2; each wave owns 4x4 16x16x32 MFMA tiles. BK=32.
// XOR swizzle on k-groups kills the 8-way ds_read_b128 bank conflict
// (R1->R2: SQ_LDS_BANK_CONFLICT 6.29M -> 0; kept since it's free).
// ---------------------------------------------------------------------------
__device__ __forceinline__ void gemm_core(const short* __restrict__ A,
                                          const short* __restrict__ Bt,
                                          int lda, int ldb,
                                          int row0, int col0, int kIters,
                                          f32x4 acc[4][4],
                                          short* lA, short* lB) {
  const int tid  = threadIdx.x;
  const int wave = tid >> 6;
  const int lane = tid & 63;
  const int quad = lane >> 4;
  const int l16  = lane & 15;

  const f32x4 zero = {0.f, 0.f, 0.f, 0.f};
#pragma unroll
  for (int i = 0; i < 4; ++i)
#pragma unroll
    for (int j = 0; j < 4; ++j) acc[i][j] = zero;

  const int lrow = tid >> 2;
  const int swz  = (lrow >> 1) & 3;
  const int lcol = ((tid & 3) ^ swz) * 8;
  const short* A1 = A + (size_t)(row0 + lrow) * lda + lcol;
  const short* A2 = A + (size_t)(row0 + lrow + 64) * lda + lcol;
  const short* B1 = Bt + (size_t)(col0 + lrow) * ldb + lcol;
  const short* B2 = Bt + (size_t)(col0 + lrow + 64) * ldb + lcol;

  short* lA1 = lA + wave * 512;
  short* lA2 = lA + 2048 + wave * 512;
  short* lB1 = lB + wave * 512;
  short* lB2 = lB + 2048 + wave * 512;

  const int rswz = (l16 >> 1) & 3;
  const short* aBase = lA + ((wave >> 1) * 64 + l16) * 32 + (quad ^ rswz) * 8;
  const short* bBase = lB + ((wave & 1) * 64 + l16) * 32 + (quad ^ rswz) * 8;

  for (int it = 0; it < kIters; ++it) {
    const int k0 = it * 32;
    gll16(A1 + k0, lA1);
    gll16(A2 + k0, lA2);
    gll16(B1 + k0, lB1);
    gll16(B2 + k0, lB2);
    __syncthreads();

    short8 af[4], bfr[4];
#pragma unroll
    for (int i = 0; i < 4; ++i) af[i] = *(const short8*)(aBase + i * 16 * 32);
#pragma unroll
    for (int j = 0; j < 4; ++j) bfr[j] = *(const short8*)(bBase + j * 16 * 32);
#pragma unroll
    for (int i = 0; i < 4; ++i)
#pragma unroll
      for (int j = 0; j < 4; ++j)
        acc[i][j] = __builtin_amdgcn_mfma_f32_16x16x32_bf16(af[i], bfr[j], acc[i][j], 0, 0, 0);
    __syncthreads();
  }
}

// C/D layout: row = quad*4 + reg, col = l16  (verified m89)
#define EPILOGUE_VARS                         \
  const int lane = threadIdx.x & 63;          \
  const int wave = threadIdx.x >> 6;          \
  const int quad = lane >> 4;                 \
  const int l16  = lane & 15;                 \
  const int rb   = (wave >> 1) * 64;          \
  const int cb   = (wave & 1) * 64;

// ---------------------------------------------------------------------------
// setup: blocks [0,8192) cast X->Xb; [8192,11264) transpose W->Wt;
//        [11264,11272) zero rowsum.
__global__ __launch_bounds__(256) void setup_kernel(const float* __restrict__ X,
                                                    const float* __restrict__ W,
                                                    short* __restrict__ Xb,
                                                    short* __restrict__ Wt,
                                                    float* __restrict__ rs) {
  const int bid = blockIdx.x;
  if (bid < 8192) {
    const int i = (bid * 256 + threadIdx.x) * 4;
    const f32x4 v = *(const f32x4*)(X + i);
    s16x4 o;
    o.x = f2bf(v.x); o.y = f2bf(v.y); o.z = f2bf(v.z); o.w = f2bf(v.w);
    *(s16x4*)(Xb + i) = o;
  } else if (bid < 11264) {
    __shared__ float tile[32][33];
    const int r  = bid - 8192;
    const int ni = r % 96;
    const int ki = r / 96;
    const int tx = threadIdx.x & 31;
    const int ty = threadIdx.x >> 5;
#pragma unroll
    for (int rr = 0; rr < 4; ++rr)
      tile[ty + rr * 8][tx] = W[(size_t)(ki * 32 + ty + rr * 8) * 3072 + ni * 32 + tx];
    __syncthreads();
#pragma unroll
    for (int rr = 0; rr < 4; ++rr)
      Wt[(size_t)(ni * 32 + ty + rr * 8) * 1024 + ki * 32 + tx] = f2bf(tile[tx][ty + rr * 8]);
  } else {
    const int i = (bid - 11264) * 1024 + threadIdx.x * 4;
    const f32x4 zero = {0.f, 0.f, 0.f, 0.f};
    *(f32x4*)(rs + i) = zero;
  }
}

// QKV: [8192x1024] x Wt[3072x1024]^T -> Q,K,V bf16 (column split)
__global__ __launch_bounds__(256) void qkv_gemm_kernel(const short* __restrict__ Xb,
                                                       const short* __restrict__ Wt,
                                                       short* __restrict__ Q,
                                                       short* __restrict__ K,
                                                       short* __restrict__ V) {
  __shared__ short lA[4096], lB[4096];
  const int br = blockIdx.x / 24;
  const int bc = blockIdx.x % 24;
  f32x4 acc[4][4];
  gemm_core(Xb, Wt, 1024, 1024, br * 128, bc * 128, 32, acc, lA, lB);

  EPILOGUE_VARS
  const int rbase = br * 128 + rb;
  const int cbase = bc * 128 + cb;
#pragma unroll
  for (int i = 0; i < 4; ++i)
#pragma unroll
    for (int j = 0; j < 4; ++j) {
      const int col = cbase + j * 16 + l16;
      short* dst;
      int n;
      if (col < 1024)      { dst = Q; n = col; }
      else if (col < 2048) { dst = K; n = col - 1024; }
      else                 { dst = V; n = col - 2048; }
#pragma unroll
      for (int r = 0; r < 4; ++r) {
        const int row = rbase + i * 16 + quad * 4 + r;
        dst[(size_t)row * 1024 + n] = f2bf(acc[i][j][r]);
      }
    }
}

// Fused: blocks [0,544) compute E = exp(QK^T/32) on lower-triangle tiles,
// causal-masked on diagonal tiles, + per-row partial sums -> atomicAdd(rs).
// Blocks [544, 544+8192) transpose V -> Vt (fills CUs idle during the
// under-occupied 544-block GEMM phase).
__global__ __launch_bounds__(256) void qk_tv_kernel(const short* __restrict__ Q,
                                                    const short* __restrict__ K,
                                                    const short* __restrict__ V,
                                                    short* __restrict__ E,
                                                    short* __restrict__ Vt,
                                                    float* __restrict__ rs) {
  __shared__ short lA[4096], lB[4096];
  if (blockIdx.x < 544) {
    const int b  = blockIdx.x / 136;
    const int tt = blockIdx.x % 136;
    int qi = 0;
    while ((qi + 1) * (qi + 2) / 2 <= tt) qi++;
    const int ki = tt - qi * (qi + 1) / 2;

    f32x4 acc[4][4];
    const short* Qb = Q + (size_t)b * 2048 * 1024;
    const short* Kb = K + (size_t)b * 2048 * 1024;
    gemm_core(Qb, Kb, 1024, 1024, qi * 128, ki * 128, 32, acc, lA, lB);

    EPILOGUE_VARS
    short* Eb  = E + (size_t)b * 2048 * 2048;
    float* rsb = rs + b * 2048;
    const int rbase = qi * 128 + rb;
    const int cbase = ki * 128 + cb;
    const bool diag = (qi == ki);
#pragma unroll
    for (int i = 0; i < 4; ++i)
#pragma unroll
      for (int r = 0; r < 4; ++r) {
        const int row = rbase + i * 16 + quad * 4 + r;
        float partial = 0.f;
#pragma unroll
        for (int j = 0; j < 4; ++j) {
          const int col = cbase + j * 16 + l16;
          float e = __expf(acc[i][j][r] * 0.03125f);
          if (diag && col > row) e = 0.f;
          partial += e;
          Eb[(size_t)row * 2048 + col] = f2bf(e);
        }
        // reduce over the 16 lanes of this quad (same row)
        partial += __shfl_xor(partial, 1);
        partial += __shfl_xor(partial, 2);
        partial += __shfl_xor(partial, 4);
        partial += __shfl_xor(partial, 8);
        if (l16 == 0) atomicAdd(rsb + row, partial);
      }
  } else {
    // transpose V[b][2048][1024] -> Vt[b][1024][2048]
    short (*tile)[33] = (short(*)[33])lA;  // 32x33 shorts fits in lA
    const int rblk = blockIdx.x - 544;
    const int b  = rblk >> 11;
    const int r  = rblk & 2047;
    const int si = r >> 5;
    const int di = r & 31;
    const short* Vb  = V + (size_t)b * 2048 * 1024;
    short*       Vtb = Vt + (size_t)b * 1024 * 2048;
    const int tx = threadIdx.x & 31;
    const int ty = threadIdx.x >> 5;
#pragma unroll
    for (int rr = 0; rr < 4; ++rr)
      tile[ty + rr * 8][tx] = Vb[(size_t)(si * 32 + ty + rr * 8) * 1024 + di * 32 + tx];
    __syncthreads();
#pragma unroll
    for (int rr = 0; rr < 4; ++rr)
      Vtb[(size_t)(di * 32 + ty + rr * 8) * 2048 + si * 32 + tx] = tile[tx][ty + rr * 8];
  }
}

// out = (E x V) / rowsum.  A = E[2048x2048] bf16, Bt = Vt[1024x2048] bf16.
// per-q-tile causal k-limit; heavy tiles (large qi) scheduled first.
__global__ __launch_bounds__(256) void pv_gemm_kernel(const short* __restrict__ E,
                                                      const short* __restrict__ Vt,
                                                      const float* __restrict__ rs,
                                                      float* __restrict__ out) {
  const int b  = blockIdx.x >> 7;
  const int r  = blockIdx.x & 127;
  const int qi = 15 - (r >> 3);
  const int dj = r & 7;

  __shared__ short lA[4096], lB[4096];
  f32x4 acc[4][4];
  const short* Eb  = E + (size_t)b * 2048 * 2048;
  const short* Vtb = Vt + (size_t)b * 1024 * 2048;
  gemm_core(Eb, Vtb, 2048, 2048, qi * 128, dj * 128, (qi + 1) * 4, acc, lA, lB);

  EPILOGUE_VARS
  float* ob = out + (size_t)b * 2048 * 1024;
  const float* rsb = rs + b * 2048;
  const int rbase = qi * 128 + rb;
  const int cbase = dj * 128 + cb;
#pragma unroll
  for (int i = 0; i < 4; ++i)
#pragma unroll
    for (int r2 = 0; r2 < 4; ++r2) {
      const int row = rbase + i * 16 + quad * 4 + r2;
      const float inv = 1.f / rsb[row];
#pragma unroll
      for (int j = 0; j < 4; ++j) {
        const int col = cbase + j * 16 + l16;
        ob[(size_t)row * 1024 + col] = acc[i][j][r2] * inv;
      }
    }
}

// ---------------------------------------------------------------------------
extern "C" void kernel_launch(void* const* d_in, const int* in_sizes, int n_in,
                              void* d_out, int out_size, void* d_ws, size_t ws_size,
                              hipStream_t stream) {
  const float* X = (const float*)d_in[0];
  const float* W = (const float*)d_in[1];
  float* out = (float*)d_out;
  char* w = (char*)d_ws;

  short* Xb = (short*)(w + 0);
  short* Wt = (short*)(w + 16777216);
  short* E  = (short*)(w + 0);          // overlays Xb,Wt (dead after qkv)
  short* V  = (short*)(w + 33554432);
  float* rs = (float*)(w + 50331648);
  short* Q  = (short*)(w + 67108864);
  short* K  = (short*)(w + 83886080);
  short* Vt = (short*)(w + 100663296);

  hipLaunchKernelGGL(setup_kernel,    dim3(11272), dim3(256), 0, stream, X, W, Xb, Wt, rs);
  hipLaunchKernelGGL(qkv_gemm_kernel, dim3(1536),  dim3(256), 0, stream, Xb, Wt, Q, K, V);
  hipLaunchKernelGGL(qk_tv_kernel,    dim3(8736),  dim3(256), 0, stream, Q, K, V, E, Vt, rs);
  hipLaunchKernelGGL(pv_gemm_kernel,  dim3(512),   dim3(256), 0, stream, E, Vt, rs, out);
}

// Round 4
// 259.622 us; speedup vs baseline: 1.0839x; 1.0071x over previous
//
#include <hip/hip_runtime.h>
#include <hip/hip_bf16.h>

// B=4, S=2048, D=1024.  M = B*S = 8192.
// Workspace layout (bytes), total 112 MB:
//   [0,         33554432)  : E bf16 (4*2048*2048) = exp(scores) -- written by qk
//     overlay (dead before qk runs):
//     [0,         16777216) : Xb  bf16 (8192*1024)
//     [16777216,  23068672) : Wt  bf16 (3072*1024)
//   [33554432,  50331648)  : V   bf16 (8192*1024)
//   [50331648,  50364416)  : rowsum fp32 (8192)  (zeroed by setup kernel)
//   [67108864,  83886080)  : Q bf16 (8192*1024)
//   [83886080, 100663296)  : K bf16 (8192*1024)
//   [100663296,117440512)  : Vt bf16 (4*1024*2048)
//
// Pipeline (4 launches):
//   setup   : cast X->bf16, transpose W -> Wt bf16, zero rowsum
//   qkv     : [8192x1024] x Wt^T -> Q,K,V
//   qk+tv   : lower-tri tiles E=exp(QK^T/32) + row-partial sums (atomicAdd);
//             co-scheduled extra blocks transpose V -> Vt (fills idle CUs)
//   pv      : out = (E x V) / rowsum   (per-q-tile causal k-limit)
//
// R3->R4: BK=32 -> BK=64.  R3 analysis: ~830 cyc per K-iteration vs 77-cyc
// MFMA floor and 256-cyc LDS floor -> barrier-drain latency bound.  BK=64
// halves the number of vmcnt(0)+barrier drains per block.  LDS 16->32 KB
// (still < the 5-blocks/CU LDS limit; occupancy is VGPR-bound).

typedef __attribute__((ext_vector_type(8))) short short8;
typedef __attribute__((ext_vector_type(4))) short s16x4;
typedef __attribute__((ext_vector_type(4))) float f32x4;

__device__ __forceinline__ short f2bf(float f) {
  __hip_bfloat16 h = __float2bfloat16(f);
  return *reinterpret_cast<short*>(&h);
}

__device__ __forceinline__ void gll16(const void* g, void* l) {
  __builtin_amdgcn_global_load_lds((const __attribute__((address_space(1))) void*)g,
                                   (__attribute__((address_space(3))) void*)l,
                                   16, 0, 0);
}

// ---------------------------------------------------------------------------
// 128x128-tile GEMM core, BK=64: C = A[M][K] * Bt[N][K]^T  (bf16, fp32 acc)
// 256 threads = 4 waves in 2x2; each wave owns 4x4 16x16x32 MFMA tiles,
// two K-steps (s=0,1) per staged LDS tile.
//
// LDS tile: 128 rows x 64 shorts (128 B).  Row r stores k-group kg (16 B
// granules, kg in [0,8)) at slot kg ^ (r&7).  global_load_lds forces
// dest = wave-uniform base + lane*16B, so the permutation is applied on the
// GLOBAL source address at staging; fragment reads XOR-undo it.  Every 8
// consecutive lanes of a ds_read_b128 then cover all eight 16B spans of a
// 128B line -> conflict-free (verified pattern: R1->R2 conflicts 6.3M -> 0).
// ---------------------------------------------------------------------------
__device__ __forceinline__ void gemm_core(const short* __restrict__ A,
                                          const short* __restrict__ Bt,
                                          int lda, int ldb,
                                          int row0, int col0, int kIters,
                                          f32x4 acc[4][4],
                                          short* lA, short* lB) {
  const int tid  = threadIdx.x;
  const int wave = tid >> 6;
  const int lane = tid & 63;
  const int quad = lane >> 4;
  const int l16  = lane & 15;

  const f32x4 zero = {0.f, 0.f, 0.f, 0.f};
#pragma unroll
  for (int i = 0; i < 4; ++i)
#pragma unroll
    for (int j = 0; j < 4; ++j) acc[i][j] = zero;

  // staging: thread t owns 16B chunks t+256q (q=0..3) of each tile.
  // chunk c -> row c>>3 (= srow+32q), slot t&7; fetches global kg = slot^(row&7).
  // (srow+32q)&7 == srow&7, so one XOR serves all four sets.
  const int srow = tid >> 3;                    // 0..31
  const int gcol = ((tid & 7) ^ (srow & 7)) * 8;
  const short* A1 = A + (size_t)(row0 + srow) * lda + gcol;
  const short* A2 = A + (size_t)(row0 + srow + 32) * lda + gcol;
  const short* A3 = A + (size_t)(row0 + srow + 64) * lda + gcol;
  const short* A4 = A + (size_t)(row0 + srow + 96) * lda + gcol;
  const short* B1 = Bt + (size_t)(col0 + srow) * ldb + gcol;
  const short* B2 = Bt + (size_t)(col0 + srow + 32) * ldb + gcol;
  const short* B3 = Bt + (size_t)(col0 + srow + 64) * ldb + gcol;
  const short* B4 = Bt + (size_t)(col0 + srow + 96) * ldb + gcol;

  // wave-uniform LDS bases: set q at byte wave*1024 + q*4096 (short offsets /2)
  short* lA1 = lA + wave * 512;
  short* lA2 = lA + 2048 + wave * 512;
  short* lA3 = lA + 4096 + wave * 512;
  short* lA4 = lA + 6144 + wave * 512;
  short* lB1 = lB + wave * 512;
  short* lB2 = lB + 2048 + wave * 512;
  short* lB3 = lB + 4096 + wave * 512;
  short* lB4 = lB + 6144 + wave * 512;

  // fragment rows: A row m = (wave>>1)*64 + i*16 + l16; (row&7)==l16&7 for all i.
  const int rswz  = l16 & 7;
  const int slot0 = (quad ^ rswz) * 8;         // K-step s=0: kg = quad
  const int slot1 = ((4 + quad) ^ rswz) * 8;   // K-step s=1: kg = 4+quad
  const short* aRow = lA + ((wave >> 1) * 64 + l16) * 64;
  const short* bRow = lB + ((wave & 1) * 64 + l16) * 64;

  for (int it = 0; it < kIters; ++it) {
    const int k0 = it * 64;
    gll16(A1 + k0, lA1);
    gll16(A2 + k0, lA2);
    gll16(A3 + k0, lA3);
    gll16(A4 + k0, lA4);
    gll16(B1 + k0, lB1);
    gll16(B2 + k0, lB2);
    gll16(B3 + k0, lB3);
    gll16(B4 + k0, lB4);
    __syncthreads();   // drains vmcnt before barrier

#pragma unroll
    for (int s = 0; s < 2; ++s) {
      const int so = s ? slot1 : slot0;
      short8 af[4], bfr[4];
#pragma unroll
      for (int i = 0; i < 4; ++i) af[i] = *(const short8*)(aRow + i * 1024 + so);
#pragma unroll
      for (int j = 0; j < 4; ++j) bfr[j] = *(const short8*)(bRow + j * 1024 + so);
#pragma unroll
      for (int i = 0; i < 4; ++i)
#pragma unroll
        for (int j = 0; j < 4; ++j)
          acc[i][j] = __builtin_amdgcn_mfma_f32_16x16x32_bf16(af[i], bfr[j], acc[i][j], 0, 0, 0);
    }
    __syncthreads();
  }
}

// C/D layout: row = quad*4 + reg, col = l16  (verified m89)
#define EPILOGUE_VARS                         \
  const int lane = threadIdx.x & 63;          \
  const int wave = threadIdx.x >> 6;          \
  const int quad = lane >> 4;                 \
  const int l16  = lane & 15;                 \
  const int rb   = (wave >> 1) * 64;          \
  const int cb   = (wave & 1) * 64;

// ---------------------------------------------------------------------------
// setup: blocks [0,8192) cast X->Xb; [8192,11264) transpose W->Wt;
//        [11264,11272) zero rowsum.
__global__ __launch_bounds__(256) void setup_kernel(const float* __restrict__ X,
                                                    const float* __restrict__ W,
                                                    short* __restrict__ Xb,
                                                    short* __restrict__ Wt,
                                                    float* __restrict__ rs) {
  const int bid = blockIdx.x;
  if (bid < 8192) {
    const int i = (bid * 256 + threadIdx.x) * 4;
    const f32x4 v = *(const f32x4*)(X + i);
    s16x4 o;
    o.x = f2bf(v.x); o.y = f2bf(v.y); o.z = f2bf(v.z); o.w = f2bf(v.w);
    *(s16x4*)(Xb + i) = o;
  } else if (bid < 11264) {
    __shared__ float tile[32][33];
    const int r  = bid - 8192;
    const int ni = r % 96;
    const int ki = r / 96;
    const int tx = threadIdx.x & 31;
    const int ty = threadIdx.x >> 5;
#pragma unroll
    for (int rr = 0; rr < 4; ++rr)
      tile[ty + rr * 8][tx] = W[(size_t)(ki * 32 + ty + rr * 8) * 3072 + ni * 32 + tx];
    __syncthreads();
#pragma unroll
    for (int rr = 0; rr < 4; ++rr)
      Wt[(size_t)(ni * 32 + ty + rr * 8) * 1024 + ki * 32 + tx] = f2bf(tile[tx][ty + rr * 8]);
  } else {
    const int i = (bid - 11264) * 1024 + threadIdx.x * 4;
    const f32x4 zero = {0.f, 0.f, 0.f, 0.f};
    *(f32x4*)(rs + i) = zero;
  }
}

// QKV: [8192x1024] x Wt[3072x1024]^T -> Q,K,V bf16 (column split)
__global__ __launch_bounds__(256) void qkv_gemm_kernel(const short* __restrict__ Xb,
                                                       const short* __restrict__ Wt,
                                                       short* __restrict__ Q,
                                                       short* __restrict__ K,
                                                       short* __restrict__ V) {
  __shared__ short lA[8192], lB[8192];
  const int br = blockIdx.x / 24;
  const int bc = blockIdx.x % 24;
  f32x4 acc[4][4];
  gemm_core(Xb, Wt, 1024, 1024, br * 128, bc * 128, 16, acc, lA, lB);

  EPILOGUE_VARS
  const int rbase = br * 128 + rb;
  const int cbase = bc * 128 + cb;
#pragma unroll
  for (int i = 0; i < 4; ++i)
#pragma unroll
    for (int j = 0; j < 4; ++j) {
      const int col = cbase + j * 16 + l16;
      short* dst;
      int n;
      if (col < 1024)      { dst = Q; n = col; }
      else if (col < 2048) { dst = K; n = col - 1024; }
      else                 { dst = V; n = col - 2048; }
#pragma unroll
      for (int r = 0; r < 4; ++r) {
        const int row = rbase + i * 16 + quad * 4 + r;
        dst[(size_t)row * 1024 + n] = f2bf(acc[i][j][r]);
      }
    }
}

// Fused: blocks [0,544) compute E = exp(QK^T/32) on lower-triangle tiles,
// causal-masked on diagonal tiles, + per-row partial sums -> atomicAdd(rs).
// Blocks [544, 544+8192) transpose V -> Vt (fills CUs idle during the
// under-occupied 544-block GEMM phase).
__global__ __launch_bounds__(256) void qk_tv_kernel(const short* __restrict__ Q,
                                                    const short* __restrict__ K,
                                                    const short* __restrict__ V,
                                                    short* __restrict__ E,
                                                    short* __restrict__ Vt,
                                                    float* __restrict__ rs) {
  __shared__ short lA[8192], lB[8192];
  if (blockIdx.x < 544) {
    const int b  = blockIdx.x / 136;
    const int tt = blockIdx.x % 136;
    int qi = 0;
    while ((qi + 1) * (qi + 2) / 2 <= tt) qi++;
    const int ki = tt - qi * (qi + 1) / 2;

    f32x4 acc[4][4];
    const short* Qb = Q + (size_t)b * 2048 * 1024;
    const short* Kb = K + (size_t)b * 2048 * 1024;
    gemm_core(Qb, Kb, 1024, 1024, qi * 128, ki * 128, 16, acc, lA, lB);

    EPILOGUE_VARS
    short* Eb  = E + (size_t)b * 2048 * 2048;
    float* rsb = rs + b * 2048;
    const int rbase = qi * 128 + rb;
    const int cbase = ki * 128 + cb;
    const bool diag = (qi == ki);
#pragma unroll
    for (int i = 0; i < 4; ++i)
#pragma unroll
      for (int r = 0; r < 4; ++r) {
        const int row = rbase + i * 16 + quad * 4 + r;
        float partial = 0.f;
#pragma unroll
        for (int j = 0; j < 4; ++j) {
          const int col = cbase + j * 16 + l16;
          float e = __expf(acc[i][j][r] * 0.03125f);
          if (diag && col > row) e = 0.f;
          partial += e;
          Eb[(size_t)row * 2048 + col] = f2bf(e);
        }
        partial += __shfl_xor(partial, 1);
        partial += __shfl_xor(partial, 2);
        partial += __shfl_xor(partial, 4);
        partial += __shfl_xor(partial, 8);
        if (l16 == 0) atomicAdd(rsb + row, partial);
      }
  } else {
    // transpose V[b][2048][1024] -> Vt[b][1024][2048]
    short (*tile)[33] = (short(*)[33])lA;  // 32x33 shorts fits in lA
    const int rblk = blockIdx.x - 544;
    const int b  = rblk >> 11;
    const int r  = rblk & 2047;
    const int si = r >> 5;
    const int di = r & 31;
    const short* Vb  = V + (size_t)b * 2048 * 1024;
    short*       Vtb = Vt + (size_t)b * 1024 * 2048;
    const int tx = threadIdx.x & 31;
    const int ty = threadIdx.x >> 5;
#pragma unroll
    for (int rr = 0; rr < 4; ++rr)
      tile[ty + rr * 8][tx] = Vb[(size_t)(si * 32 + ty + rr * 8) * 1024 + di * 32 + tx];
    __syncthreads();
#pragma unroll
    for (int rr = 0; rr < 4; ++rr)
      Vtb[(size_t)(di * 32 + ty + rr * 8) * 2048 + si * 32 + tx] = tile[tx][ty + rr * 8];
  }
}

// out = (E x V) / rowsum.  A = E[2048x2048] bf16, Bt = Vt[1024x2048] bf16.
// per-q-tile causal k-limit; heavy tiles (large qi) scheduled first.
__global__ __launch_bounds__(256) void pv_gemm_kernel(const short* __restrict__ E,
                                                      const short* __restrict__ Vt,
                                                      const float* __restrict__ rs,
                                                      float* __restrict__ out) {
  const int b  = blockIdx.x >> 7;
  const int r  = blockIdx.x & 127;
  const int qi = 15 - (r >> 3);
  const int dj = r & 7;

  __shared__ short lA[8192], lB[8192];
  f32x4 acc[4][4];
  const short* Eb  = E + (size_t)b * 2048 * 2048;
  const short* Vtb = Vt + (size_t)b * 1024 * 2048;
  gemm_core(Eb, Vtb, 2048, 2048, qi * 128, dj * 128, (qi + 1) * 2, acc, lA, lB);

  EPILOGUE_VARS
  float* ob = out + (size_t)b * 2048 * 1024;
  const float* rsb = rs + b * 2048;
  const int rbase = qi * 128 + rb;
  const int cbase = dj * 128 + cb;
#pragma unroll
  for (int i = 0; i < 4; ++i)
#pragma unroll
    for (int r2 = 0; r2 < 4; ++r2) {
      const int row = rbase + i * 16 + quad * 4 + r2;
      const float inv = 1.f / rsb[row];
#pragma unroll
      for (int j = 0; j < 4; ++j) {
        const int col = cbase + j * 16 + l16;
        ob[(size_t)row * 1024 + col] = acc[i][j][r2] * inv;
      }
    }
}

// ---------------------------------------------------------------------------
extern "C" void kernel_launch(void* const* d_in, const int* in_sizes, int n_in,
                              void* d_out, int out_size, void* d_ws, size_t ws_size,
                              hipStream_t stream) {
  const float* X = (const float*)d_in[0];
  const float* W = (const float*)d_in[1];
  float* out = (float*)d_out;
  char* w = (char*)d_ws;

  short* Xb = (short*)(w + 0);
  short* Wt = (short*)(w + 16777216);
  short* E  = (short*)(w + 0);          // overlays Xb,Wt (dead after qkv)
  short* V  = (short*)(w + 33554432);
  float* rs = (float*)(w + 50331648);
  short* Q  = (short*)(w + 67108864);
  short* K  = (short*)(w + 83886080);
  short* Vt = (short*)(w + 100663296);

  hipLaunchKernelGGL(setup_kernel,    dim3(11272), dim3(256), 0, stream, X, W, Xb, Wt, rs);
  hipLaunchKernelGGL(qkv_gemm_kernel, dim3(1536),  dim3(256), 0, stream, Xb, Wt, Q, K, V);
  hipLaunchKernelGGL(qk_tv_kernel,    dim3(8736),  dim3(256), 0, stream, Q, K, V, E, Vt, rs);
  hipLaunchKernelGGL(pv_gemm_kernel,  dim3(512),   dim3(256), 0, stream, E, Vt, rs, out);
}

// Round 5
// 255.424 us; speedup vs baseline: 1.1017x; 1.0164x over previous
//
#include <hip/hip_runtime.h>
#include <hip/hip_bf16.h>

// B=4, S=2048, D=1024.  M = B*S = 8192.
// Workspace layout (bytes):
//   [0,         33554432)  : E bf16 (4*2048*2048) = exp(scores) -- written by qk
//     overlay (dead before qk runs):
//     [0,         16777216) : Xb  bf16 (8192*1024)
//     [16777216,  23068672) : Wt  bf16 (3072*1024)
//   [50331648,  50364416)  : rowsum fp32 (8192)  (zeroed by setup kernel)
//   [67108864,  83886080)  : Q bf16 (8192*1024)
//   [83886080, 100663296)  : K bf16 (8192*1024)
//   [100663296,117440512)  : Vt bf16 (4*1024*2048)  -- written DIRECTLY by qkv
//
// Pipeline (4 launches):
//   setup : cast X->bf16, transpose W -> Wt bf16, zero rowsum
//   qkv   : [8192x1024] x Wt^T -> Q, K row-major; V written directly as Vt
//           (MFMA C-layout gives each lane 4 consecutive s for fixed d ->
//            packed 8B stores; kills the separate transpose kernel + 32 MB)
//   qk    : lower-tri tiles E=exp(QK^T/32) + row sums (atomicAdd)
//   pv    : out = (E x V) / rowsum   (per-q-tile causal k-limit)
//
// R4 post-mortem: qkv at 805 TF (structure plateau); BK=64 kept.  The
// transpose-V work and its contention with qk are eliminated this round.

typedef __attribute__((ext_vector_type(8))) short short8;
typedef __attribute__((ext_vector_type(4))) short s16x4;
typedef __attribute__((ext_vector_type(4))) float f32x4;

__device__ __forceinline__ short f2bf(float f) {
  __hip_bfloat16 h = __float2bfloat16(f);
  return *reinterpret_cast<short*>(&h);
}

__device__ __forceinline__ void gll16(const void* g, void* l) {
  __builtin_amdgcn_global_load_lds((const __attribute__((address_space(1))) void*)g,
                                   (__attribute__((address_space(3))) void*)l,
                                   16, 0, 0);
}

// ---------------------------------------------------------------------------
// 128x128-tile GEMM core, BK=64: C = A[M][K] * Bt[N][K]^T  (bf16, fp32 acc)
// 256 threads = 4 waves in 2x2; each wave owns 4x4 16x16x32 MFMA tiles,
// two K-steps per staged LDS tile.  XOR bank swizzle: row r stores k-group
// kg at slot kg ^ (r&7); staging applies it on the GLOBAL source address
// (global_load_lds dest is lane-forced), fragment reads undo it.
// (R1->R2 evidence: conflicts 6.3M -> 0.)
// ---------------------------------------------------------------------------
__device__ __forceinline__ void gemm_core(const short* __restrict__ A,
                                          const short* __restrict__ Bt,
                                          int lda, int ldb,
                                          int row0, int col0, int kIters,
                                          f32x4 acc[4][4],
                                          short* lA, short* lB) {
  const int tid  = threadIdx.x;
  const int wave = tid >> 6;
  const int lane = tid & 63;
  const int quad = lane >> 4;
  const int l16  = lane & 15;

  const f32x4 zero = {0.f, 0.f, 0.f, 0.f};
#pragma unroll
  for (int i = 0; i < 4; ++i)
#pragma unroll
    for (int j = 0; j < 4; ++j) acc[i][j] = zero;

  const int srow = tid >> 3;                    // 0..31
  const int gcol = ((tid & 7) ^ (srow & 7)) * 8;
  const short* A1 = A + (size_t)(row0 + srow) * lda + gcol;
  const short* A2 = A + (size_t)(row0 + srow + 32) * lda + gcol;
  const short* A3 = A + (size_t)(row0 + srow + 64) * lda + gcol;
  const short* A4 = A + (size_t)(row0 + srow + 96) * lda + gcol;
  const short* B1 = Bt + (size_t)(col0 + srow) * ldb + gcol;
  const short* B2 = Bt + (size_t)(col0 + srow + 32) * ldb + gcol;
  const short* B3 = Bt + (size_t)(col0 + srow + 64) * ldb + gcol;
  const short* B4 = Bt + (size_t)(col0 + srow + 96) * ldb + gcol;

  short* lA1 = lA + wave * 512;
  short* lA2 = lA + 2048 + wave * 512;
  short* lA3 = lA + 4096 + wave * 512;
  short* lA4 = lA + 6144 + wave * 512;
  short* lB1 = lB + wave * 512;
  short* lB2 = lB + 2048 + wave * 512;
  short* lB3 = lB + 4096 + wave * 512;
  short* lB4 = lB + 6144 + wave * 512;

  const int rswz  = l16 & 7;
  const int slot0 = (quad ^ rswz) * 8;
  const int slot1 = ((4 + quad) ^ rswz) * 8;
  const short* aRow = lA + ((wave >> 1) * 64 + l16) * 64;
  const short* bRow = lB + ((wave & 1) * 64 + l16) * 64;

  for (int it = 0; it < kIters; ++it) {
    const int k0 = it * 64;
    gll16(A1 + k0, lA1);
    gll16(A2 + k0, lA2);
    gll16(A3 + k0, lA3);
    gll16(A4 + k0, lA4);
    gll16(B1 + k0, lB1);
    gll16(B2 + k0, lB2);
    gll16(B3 + k0, lB3);
    gll16(B4 + k0, lB4);
    __syncthreads();

#pragma unroll
    for (int s = 0; s < 2; ++s) {
      const int so = s ? slot1 : slot0;
      short8 af[4], bfr[4];
#pragma unroll
      for (int i = 0; i < 4; ++i) af[i] = *(const short8*)(aRow + i * 1024 + so);
#pragma unroll
      for (int j = 0; j < 4; ++j) bfr[j] = *(const short8*)(bRow + j * 1024 + so);
#pragma unroll
      for (int i = 0; i < 4; ++i)
#pragma unroll
        for (int j = 0; j < 4; ++j)
          acc[i][j] = __builtin_amdgcn_mfma_f32_16x16x32_bf16(af[i], bfr[j], acc[i][j], 0, 0, 0);
    }
    __syncthreads();
  }
}

// C/D layout: row = quad*4 + reg, col = l16  (verified m89)
#define EPILOGUE_VARS                         \
  const int lane = threadIdx.x & 63;          \
  const int wave = threadIdx.x >> 6;          \
  const int quad = lane >> 4;                 \
  const int l16  = lane & 15;                 \
  const int rb   = (wave >> 1) * 64;          \
  const int cb   = (wave & 1) * 64;

// ---------------------------------------------------------------------------
// setup: blocks [0,8192) cast X->Xb; [8192,11264) transpose W->Wt;
//        [11264,11272) zero rowsum.
__global__ __launch_bounds__(256) void setup_kernel(const float* __restrict__ X,
                                                    const float* __restrict__ W,
                                                    short* __restrict__ Xb,
                                                    short* __restrict__ Wt,
                                                    float* __restrict__ rs) {
  const int bid = blockIdx.x;
  if (bid < 8192) {
    const int i = (bid * 256 + threadIdx.x) * 4;
    const f32x4 v = *(const f32x4*)(X + i);
    s16x4 o;
    o.x = f2bf(v.x); o.y = f2bf(v.y); o.z = f2bf(v.z); o.w = f2bf(v.w);
    *(s16x4*)(Xb + i) = o;
  } else if (bid < 11264) {
    __shared__ float tile[32][33];
    const int r  = bid - 8192;
    const int ni = r % 96;
    const int ki = r / 96;
    const int tx = threadIdx.x & 31;
    const int ty = threadIdx.x >> 5;
#pragma unroll
    for (int rr = 0; rr < 4; ++rr)
      tile[ty + rr * 8][tx] = W[(size_t)(ki * 32 + ty + rr * 8) * 3072 + ni * 32 + tx];
    __syncthreads();
#pragma unroll
    for (int rr = 0; rr < 4; ++rr)
      Wt[(size_t)(ni * 32 + ty + rr * 8) * 1024 + ki * 32 + tx] = f2bf(tile[tx][ty + rr * 8]);
  } else {
    const int i = (bid - 11264) * 1024 + threadIdx.x * 4;
    const f32x4 zero = {0.f, 0.f, 0.f, 0.f};
    *(f32x4*)(rs + i) = zero;
  }
}

// QKV: [8192x1024] x Wt[3072x1024]^T.  Q,K row-major [s][d]; V-columns are
// written DIRECTLY transposed into Vt[b][d][s]: for fixed (i,j), lane l16
// holds acc[r=0..3] = 4 consecutive s for one d -> one packed 8B store.
__global__ __launch_bounds__(256) void qkv_gemm_kernel(const short* __restrict__ Xb,
                                                       const short* __restrict__ Wt,
                                                       short* __restrict__ Q,
                                                       short* __restrict__ K,
                                                       short* __restrict__ Vt) {
  __shared__ short lA[8192], lB[8192];
  const int br = blockIdx.x / 24;
  const int bc = blockIdx.x % 24;
  f32x4 acc[4][4];
  gemm_core(Xb, Wt, 1024, 1024, br * 128, bc * 128, 16, acc, lA, lB);

  EPILOGUE_VARS
  const int rbase = br * 128 + rb;
  const int cbase = bc * 128 + cb;
  if (bc < 16) {
    // Q or K (block-uniform: 128-col tile entirely within Q or K range)
#pragma unroll
    for (int i = 0; i < 4; ++i)
#pragma unroll
      for (int j = 0; j < 4; ++j) {
        const int col = cbase + j * 16 + l16;
        short* dst = (col < 1024) ? Q : K;
        const int n = col & 1023;
#pragma unroll
        for (int r = 0; r < 4; ++r) {
          const int row = rbase + i * 16 + quad * 4 + r;
          dst[(size_t)row * 1024 + n] = f2bf(acc[i][j][r]);
        }
      }
  } else {
    // V -> Vt[b][d][s] direct, packed 4x bf16 (8 B) per (i,j)
    const int b  = rbase >> 11;
    const int s0 = rbase & 2047;
    short* VtB = Vt + (size_t)b * 1024 * 2048;
#pragma unroll
    for (int i = 0; i < 4; ++i) {
      const int sb = s0 + i * 16 + quad * 4;
#pragma unroll
      for (int j = 0; j < 4; ++j) {
        const int d = cbase - 2048 + j * 16 + l16;
        s16x4 pk;
        pk.x = f2bf(acc[i][j][0]);
        pk.y = f2bf(acc[i][j][1]);
        pk.z = f2bf(acc[i][j][2]);
        pk.w = f2bf(acc[i][j][3]);
        *(s16x4*)(VtB + (size_t)d * 2048 + sb) = pk;
      }
    }
  }
}

// qk: lower-triangle tiles E = exp(QK^T/32), causal-masked on diagonal tiles,
// + per-row partial sums -> atomicAdd(rs).  544 blocks.
__global__ __launch_bounds__(256) void qk_kernel(const short* __restrict__ Q,
                                                 const short* __restrict__ K,
                                                 short* __restrict__ E,
                                                 float* __restrict__ rs) {
  __shared__ short lA[8192], lB[8192];
  const int b  = blockIdx.x / 136;
  const int tt = blockIdx.x % 136;
  int qi = 0;
  while ((qi + 1) * (qi + 2) / 2 <= tt) qi++;
  const int ki = tt - qi * (qi + 1) / 2;

  f32x4 acc[4][4];
  const short* Qb = Q + (size_t)b * 2048 * 1024;
  const short* Kb = K + (size_t)b * 2048 * 1024;
  gemm_core(Qb, Kb, 1024, 1024, qi * 128, ki * 128, 16, acc, lA, lB);

  EPILOGUE_VARS
  short* Eb  = E + (size_t)b * 2048 * 2048;
  float* rsb = rs + b * 2048;
  const int rbase = qi * 128 + rb;
  const int cbase = ki * 128 + cb;
  const bool diag = (qi == ki);
#pragma unroll
  for (int i = 0; i < 4; ++i)
#pragma unroll
    for (int r = 0; r < 4; ++r) {
      const int row = rbase + i * 16 + quad * 4 + r;
      float partial = 0.f;
#pragma unroll
      for (int j = 0; j < 4; ++j) {
        const int col = cbase + j * 16 + l16;
        float e = __expf(acc[i][j][r] * 0.03125f);
        if (diag && col > row) e = 0.f;
        partial += e;
        Eb[(size_t)row * 2048 + col] = f2bf(e);
      }
      partial += __shfl_xor(partial, 1);
      partial += __shfl_xor(partial, 2);
      partial += __shfl_xor(partial, 4);
      partial += __shfl_xor(partial, 8);
      if (l16 == 0) atomicAdd(rsb + row, partial);
    }
}

// out = (E x V) / rowsum.  A = E[2048x2048] bf16, Bt = Vt[1024x2048] bf16.
// per-q-tile causal k-limit; heavy tiles (large qi) scheduled first.
__global__ __launch_bounds__(256) void pv_gemm_kernel(const short* __restrict__ E,
                                                      const short* __restrict__ Vt,
                                                      const float* __restrict__ rs,
                                                      float* __restrict__ out) {
  const int b  = blockIdx.x >> 7;
  const int r  = blockIdx.x & 127;
  const int qi = 15 - (r >> 3);
  const int dj = r & 7;

  __shared__ short lA[8192], lB[8192];
  f32x4 acc[4][4];
  const short* Eb  = E + (size_t)b * 2048 * 2048;
  const short* Vtb = Vt + (size_t)b * 1024 * 2048;
  gemm_core(Eb, Vtb, 2048, 2048, qi * 128, dj * 128, (qi + 1) * 2, acc, lA, lB);

  EPILOGUE_VARS
  float* ob = out + (size_t)b * 2048 * 1024;
  const float* rsb = rs + b * 2048;
  const int rbase = qi * 128 + rb;
  const int cbase = dj * 128 + cb;
#pragma unroll
  for (int i = 0; i < 4; ++i)
#pragma unroll
    for (int r2 = 0; r2 < 4; ++r2) {
      const int row = rbase + i * 16 + quad * 4 + r2;
      const float inv = 1.f / rsb[row];
#pragma unroll
      for (int j = 0; j < 4; ++j) {
        const int col = cbase + j * 16 + l16;
        ob[(size_t)row * 1024 + col] = acc[i][j][r2] * inv;
      }
    }
}

// ---------------------------------------------------------------------------
extern "C" void kernel_launch(void* const* d_in, const int* in_sizes, int n_in,
                              void* d_out, int out_size, void* d_ws, size_t ws_size,
                              hipStream_t stream) {
  const float* X = (const float*)d_in[0];
  const float* W = (const float*)d_in[1];
  float* out = (float*)d_out;
  char* w = (char*)d_ws;

  short* Xb = (short*)(w + 0);
  short* Wt = (short*)(w + 16777216);
  short* E  = (short*)(w + 0);          // overlays Xb,Wt (dead after qkv)
  float* rs = (float*)(w + 50331648);
  short* Q  = (short*)(w + 67108864);
  short* K  = (short*)(w + 83886080);
  short* Vt = (short*)(w + 100663296);

  hipLaunchKernelGGL(setup_kernel,    dim3(11272), dim3(256), 0, stream, X, W, Xb, Wt, rs);
  hipLaunchKernelGGL(qkv_gemm_kernel, dim3(1536),  dim3(256), 0, stream, Xb, Wt, Q, K, Vt);
  hipLaunchKernelGGL(qk_kernel,       dim3(544),   dim3(256), 0, stream, Q, K, E, rs);
  hipLaunchKernelGGL(pv_gemm_kernel,  dim3(512),   dim3(256), 0, stream, E, Vt, rs, out);
}